// Round 15
// baseline (511.974 us; speedup 1.0000x reference)
//
#include <hip/hip_runtime.h>

// Encoder: D=4, L=16, C=64, H=W=128.
// Math: softmax_j(A_i+B_j+ba)==softmax_j(B_j); attn identical for all i;
// B = conv5(h,Weff) as GEMM into 25 tap planes T + shift-add;
// a = Wv*(g1*(sum_j P_j r_j x_j - sum_j P_j r_j mu_j)+b1)+bv.
// R17: full fp16 datapath (xh 32MB replaces f32 chain + mirror), 511us.
// R18 (this): ffn WRITE_SIZE was 67MB for 32MB logical — the epilogue
// emits 8B stores scattered across 16 c-planes/instr -> partial-sector
// write inflation at HBM. Fix: LDS-staged contiguous writeback. ffn
// stages v (fp16 16KB) into the free f1 region (chunk-rotated to avoid
// 256B-stride bank collisions), then 64B-contiguous stores/thread. tb
// stages its 25x128 T tile (6.4KB) the same way (16B/thread stores).
// Last-depth f32 d_out path keeps direct stores.

#define HW 16384
#define CHW 1048576
#define NB 64  // stat buckets; each bucket = 32 floats = one 128B line

typedef unsigned short u16;
typedef __attribute__((ext_vector_type(8))) _Float16 f16x8;
typedef __attribute__((ext_vector_type(8))) unsigned short u16x8;
typedef __attribute__((ext_vector_type(4))) float f32x4;

static __device__ __forceinline__ u16 f2h(float f) {
  union { _Float16 h; u16 u; } v;
  v.h = (_Float16)f;
  return v.u;
}
static __device__ __forceinline__ float h2f(u16 u) {
  union { u16 u; _Float16 h; } v;
  v.u = u;
  return (float)v.h;
}
// LN stats from bucketed accumulators, wave-parallel.
static __device__ __forceinline__ void ln_from_acc_wave(
    const float* acc, int l, int lane, float& mu, float& r) {
  const float invN = 1.f / 1048576.f;
  float2 v = *(const float2*)(acc + lane * 32 + 2 * l);
  float s = v.x, q = v.y;
#pragma unroll
  for (int off = 32; off > 0; off >>= 1) {
    s += __shfl_xor(s, off);
    q += __shfl_xor(q, off);
  }
  mu = s * invN;
  r = rsqrtf(q * invN - mu * mu + 1e-5f);
}

// ---- precompute fp16 MFMA fragment packs:
// pack[((t0*KT+kt)*64+lane)*8+j] = W[m=t0*16+(lane&15)][k=kt*32+(lane>>4)*8+j]
__global__ __launch_bounds__(256) void prep_kernel(
    const float* __restrict__ Wa, const float* __restrict__ Wk,
    const float* __restrict__ Wv, const float* __restrict__ W1,
    const float* __restrict__ W2, u16* __restrict__ w1pk,
    u16* __restrict__ w2pk, u16* __restrict__ wvpk, u16* __restrict__ wepk) {
  int d = blockIdx.x;
  int t = blockIdx.y * 256 + threadIdx.x;  // 0..4095
  const int STR = 256 * 16;
  const float* WaK = Wa + ((size_t)d * 128 + 64) * 25;
  const float* Wkd = Wk + d * 4096;
  for (int idx = t; idx < 2048; idx += STR) {  // Weff: m=tap(32), k=ci(64)
    int frag = idx >> 9, lane = (idx >> 3) & 63, j = idx & 7;
    int mt = frag >> 1, kt = frag & 1;
    int tap = mt * 16 + (lane & 15);
    int ci = kt * 32 + (lane >> 4) * 8 + j;
    float s = 0.f;
    if (tap < 25)
      for (int co = 0; co < 64; ++co)
        s = fmaf(WaK[co * 25 + tap], Wkd[co * 64 + ci], s);
    wepk[d * 2048 + idx] = f2h(s);
  }
  const float* Wvd = Wv + d * 4096;
  for (int idx = t; idx < 4096; idx += STR) {  // Wv: m=co(64), k=ci(64)
    int frag = idx >> 9, lane = (idx >> 3) & 63, j = idx & 7;
    int mt = frag >> 1, kt = frag & 1;
    int co = mt * 16 + (lane & 15);
    int ci = kt * 32 + (lane >> 4) * 8 + j;
    wvpk[d * 4096 + idx] = f2h(Wvd[co * 64 + ci]);
  }
  const float* W1d = W1 + d * 8192;
  for (int idx = t; idx < 8192; idx += STR) {  // W1: m=o(128), k=ci(64)
    int frag = idx >> 9, lane = (idx >> 3) & 63, j = idx & 7;
    int mt = frag >> 1, kt = frag & 1;
    int o = mt * 16 + (lane & 15);
    int ci = kt * 32 + (lane >> 4) * 8 + j;
    w1pk[d * 8192 + idx] = f2h(W1d[o * 64 + ci]);
  }
  const float* W2d = W2 + d * 8192;
  for (int idx = t; idx < 8192; idx += STR) {  // W2: m=c(64), k=o(128)
    int frag = idx >> 9, lane = (idx >> 3) & 63, j = idx & 7;
    int mt2 = frag >> 2, kt2 = frag & 3;
    int c = mt2 * 16 + (lane & 15);
    int o = kt2 * 32 + (lane >> 4) * 8 + j;
    w2pk[d * 8192 + idx] = f2h(W2d[c * 128 + o]);
  }
}

// ---- convert g1, b1 (all depths) to fp16 ----
__global__ __launch_bounds__(256) void lngb_kernel(
    const float* __restrict__ g1, const float* __restrict__ b1,
    u16* __restrict__ o1, u16* __restrict__ o2) {
  int idx = blockIdx.x * 256 + threadIdx.x;  // x4 elems
  const float* src = blockIdx.y == 0 ? g1 : b1;
  u16* dst = blockIdx.y == 0 ? o1 : o2;
  float4 v = *(const float4*)(src + (size_t)idx * 4);
  ushort4 o;
  o.x = f2h(v.x); o.y = f2h(v.y); o.z = f2h(v.z); o.w = f2h(v.w);
  *(ushort4*)(dst + (size_t)idx * 4) = o;
}

// ---- per-frame stats of x_in (bucketed) + xh fp16 write ----
__global__ __launch_bounds__(256) void stats_kernel(
    const float* __restrict__ xin, u16* __restrict__ xh,
    float* __restrict__ acc) {
  int tid = threadIdx.x;
  size_t base = (size_t)blockIdx.x * 4096;
  const float4* in4 = (const float4*)(xin + base);
  float s = 0.f, q = 0.f;
#pragma unroll
  for (int k = 0; k < 4; ++k) {
    float4 v = in4[k * 256 + tid];
    ushort4 o;
    o.x = f2h(v.x); o.y = f2h(v.y); o.z = f2h(v.z); o.w = f2h(v.w);
    *(ushort4*)(xh + base + (k * 256 + tid) * 4) = o;
    s += v.x + v.y + v.z + v.w;
    q = fmaf(v.x, v.x, q); q = fmaf(v.y, v.y, q);
    q = fmaf(v.z, v.z, q); q = fmaf(v.w, v.w, q);
  }
#pragma unroll
  for (int off = 32; off > 0; off >>= 1) {
    s += __shfl_down(s, off); q += __shfl_down(q, off);
  }
  __shared__ float ls[4], lq[4];
  int wave = tid >> 6;
  if ((tid & 63) == 0) { ls[wave] = s; lq[wave] = q; }
  __syncthreads();
  if (tid == 0) {
    int frame = blockIdx.x >> 8;
    int bkt = blockIdx.x & (NB - 1);
    atomicAdd(&acc[bkt * 32 + frame * 2], ls[0] + ls[1] + ls[2] + ls[3]);
    atomicAdd(&acc[bkt * 32 + frame * 2 + 1], lq[0] + lq[1] + lq[2] + lq[3]);
  }
}

// ---- LN1 + T GEMM (all fp16), 128 px/block; LDS-staged T writeback ----
// LDS: hb[128][72] (18432) | Tb[25][128] rotated (6400). 24832 B.
__global__ __launch_bounds__(256) void tb_kernel(
    const u16* __restrict__ xh, const u16* __restrict__ g,
    const u16* __restrict__ bln, const u16* __restrict__ wep_g,
    const float* __restrict__ accA, float* __restrict__ accBz,
    float* __restrict__ mulr, u16* __restrict__ T) {
  __shared__ __align__(16) char lds[24832];
  u16* hb = (u16*)lds;
  u16* Tb = (u16*)(lds + 18432);
  int tid = threadIdx.x;
  int l = blockIdx.y;
  int p0 = blockIdx.x << 7;
  if (blockIdx.x == 0 && blockIdx.y == 0)
    for (int i = tid; i < NB * 32; i += 256) accBz[i] = 0.f;
  int lane = tid & 63;
  float mu, r;
  ln_from_acc_wave(accA, l, lane, mu, r);
  if (blockIdx.x == 0 && tid == 0) {
    mulr[2 * l] = mu;
    mulr[2 * l + 1] = r;
  }

  // stage h[px][ci]: thread = (pq: 8px, cg: 4c); u16x8 loads everywhere
  {
    int pq = tid & 15, cg = tid >> 4;
    int px0 = pq * 8, c0 = cg * 4;
    float vv[4][8];
#pragma unroll
    for (int i = 0; i < 4; ++i) {
      int c = c0 + i;
      size_t gi = (((size_t)l * 64 + c) << 14) + p0 + px0;
      int li = (c << 14) + p0 + px0;
      u16x8 xv = *(const u16x8*)(xh + gi);
      u16x8 gv = *(const u16x8*)(g + li);
      u16x8 b8 = *(const u16x8*)(bln + li);
#pragma unroll
      for (int k = 0; k < 8; ++k)
        vv[i][k] = (h2f(xv[k]) - mu) * r * h2f(gv[k]) + h2f(b8[k]);
    }
#pragma unroll
    for (int k = 0; k < 8; ++k) {
      int row = px0 + k;
      int col = ((((c0 >> 3) + (row >> 2)) & 7) << 3) | (c0 & 7);
      ushort4 hv;
      hv.x = f2h(vv[0][k]); hv.y = f2h(vv[1][k]);
      hv.z = f2h(vv[2][k]); hv.w = f2h(vv[3][k]);
      *(ushort4*)(hb + row * 72 + col) = hv;
    }
  }
  __syncthreads();

  int wv = tid >> 6;
  int ln15 = lane & 15, quad = lane >> 4;

  f16x8 ah[2][2];
#pragma unroll
  for (int mt = 0; mt < 2; ++mt) {
    int px = (wv * 2 + mt) * 16 + ln15;
#pragma unroll
    for (int kt = 0; kt < 2; ++kt) {
      int slot = ((kt * 4 + quad) + (px >> 2)) & 7;
      ah[mt][kt] = *(const f16x8*)(hb + px * 72 + (slot << 3));
    }
  }
  const f16x8* weg = (const f16x8*)wep_g;

  f32x4 accT[2][2];
#pragma unroll
  for (int mt = 0; mt < 2; ++mt)
#pragma unroll
    for (int nt = 0; nt < 2; ++nt) accT[mt][nt] = (f32x4){0.f, 0.f, 0.f, 0.f};
#pragma unroll
  for (int nt = 0; nt < 2; ++nt) {
    f16x8 b0 = weg[(nt * 2 + 0) * 64 + lane];
    f16x8 b1w = weg[(nt * 2 + 1) * 64 + lane];
#pragma unroll
    for (int mt = 0; mt < 2; ++mt) {
      accT[mt][nt] = __builtin_amdgcn_mfma_f32_16x16x32_f16(
          ah[mt][0], b0, accT[mt][nt], 0, 0, 0);
      accT[mt][nt] = __builtin_amdgcn_mfma_f32_16x16x32_f16(
          ah[mt][1], b1w, accT[mt][nt], 0, 0, 0);
    }
  }

  // stage T tile into LDS (chunk-rotated), then contiguous writeback
#pragma unroll
  for (int mt = 0; mt < 2; ++mt) {
    int pxl = (wv * 2 + mt) * 16 + quad * 4;  // local px
#pragma unroll
    for (int nt = 0; nt < 2; ++nt) {
      int tap = nt * 16 + ln15;
      if (tap < 25) {
        ushort4 o;
        o.x = f2h(accT[mt][nt][0]); o.y = f2h(accT[mt][nt][1]);
        o.z = f2h(accT[mt][nt][2]); o.w = f2h(accT[mt][nt][3]);
        int addr = tap * 128 + ((((pxl >> 3) + tap) & 15) << 3) + (pxl & 7);
        *(ushort4*)(Tb + addr) = o;
      }
    }
  }
  __syncthreads();
  for (int idx = tid; idx < 400; idx += 256) {
    int tap = idx >> 4, k = idx & 15;
    u16x8 v = *(const u16x8*)(Tb + tap * 128 + (((k + tap) & 15) << 3));
    *(u16x8*)(T + (((size_t)l * 25 + tap) << 14) + p0 + k * 8) = v;
  }
}

// ---- fused B-from-T + softmax + hbar + Wv-GEMM + stats(x+a) ----
// 64px tile/block, grid 256. Phase A1 folds bconv (T L2-hot); phase D
// computes LN2 stats from xh (L2-hot after phase B).
__global__ __launch_bounds__(256) void attnc_kernel(
    const u16* __restrict__ xh, const u16* __restrict__ T,
    const u16* __restrict__ g1, const u16* __restrict__ b1g,
    const u16* __restrict__ wvp_g, const float* __restrict__ bv,
    const float* __restrict__ mulr, u16* __restrict__ abf,
    float* __restrict__ accB, float* __restrict__ accAz) {
  __shared__ float Bsm[16][68];
  __shared__ float Prl[16][64];
  __shared__ float scal[64];
  __shared__ __align__(16) u16 hb[64 * 72];
  __shared__ float lsq[4][32];
  int tid = threadIdx.x;
  int p0 = blockIdx.x << 6;
  if (blockIdx.x == 0)  // zero accA buckets for ffn
    for (int i = tid; i < NB * 32; i += 256) accAz[i] = 0.f;

  // phase A1: B[j][px] = sum_tap T[j][tap][px+off] (fused bconv)
  {
    int j = tid >> 4, xg = tid & 15;
    int y0 = p0 >> 7, x0 = p0 & 127;
    float acc4[4] = {0.f, 0.f, 0.f, 0.f};
    const u16* Tj = T + (((size_t)j * 25) << 14);
#pragma unroll
    for (int dy = 0; dy < 5; ++dy) {
      int yy = y0 + dy - 2;
      if (yy < 0 || yy > 127) continue;
#pragma unroll
      for (int dx = 0; dx < 5; ++dx) {
        const u16* Tt = Tj + ((dy * 5 + dx) << 14) + (yy << 7);
#pragma unroll
        for (int k = 0; k < 4; ++k) {
          int xc = x0 + xg * 4 + k + dx - 2;
          if (xc >= 0 && xc < 128) acc4[k] += h2f(Tt[xc]);
        }
      }
    }
#pragma unroll
    for (int k = 0; k < 4; ++k) Bsm[j][xg * 4 + k] = acc4[k];
  }
  __syncthreads();

  // phase A2: softmax weights (threads 0..63 own one px each)
  if (tid < 64) {
    float bj[16], m = -1e30f;
#pragma unroll
    for (int j = 0; j < 16; ++j) {
      bj[j] = Bsm[j][tid];
      m = fmaxf(m, bj[j]);
    }
    float sum = 0.f;
#pragma unroll
    for (int j = 0; j < 16; ++j) {
      bj[j] = __expf(bj[j] - m);
      sum += bj[j];
    }
    float inv = 1.f / sum;
    float sc = 0.f;
#pragma unroll
    for (int j = 0; j < 16; ++j) {
      float mu_j = mulr[2 * j], r_j = mulr[2 * j + 1];
      float prl = bj[j] * inv * r_j;
      Prl[j][tid] = prl;
      sc = fmaf(prl, mu_j, sc);
    }
    scal[tid] = sc;
  }
  __syncthreads();

  // phase B: xbar = sum_j Prl[j]*xh_j ; hbar = g1*(xbar-scal)+b1 -> hb
  {
    int c2 = tid >> 3, pxg = tid & 7;
    int px0 = pxg * 8;
    float xbar[2][8];
#pragma unroll
    for (int cc = 0; cc < 2; ++cc)
#pragma unroll
      for (int k = 0; k < 8; ++k) xbar[cc][k] = 0.f;
#pragma unroll
    for (int j = 0; j < 16; ++j) {
      float p8[8];
#pragma unroll
      for (int k = 0; k < 8; ++k) p8[k] = Prl[j][px0 + k];
#pragma unroll
      for (int cc = 0; cc < 2; ++cc) {
        int c = cc * 32 + c2;
        u16x8 xv =
            *(const u16x8*)(xh + (((size_t)j * 64 + c) << 14) + p0 + px0);
#pragma unroll
        for (int k = 0; k < 8; ++k)
          xbar[cc][k] = fmaf(p8[k], h2f(xv[k]), xbar[cc][k]);
      }
    }
    float sc8[8];
#pragma unroll
    for (int k = 0; k < 8; ++k) sc8[k] = scal[px0 + k];
#pragma unroll
    for (int cc = 0; cc < 2; ++cc) {
      int c = cc * 32 + c2;
      int li = (c << 14) + p0 + px0;
      u16x8 g8 = *(const u16x8*)(g1 + li);
      u16x8 b8 = *(const u16x8*)(b1g + li);
#pragma unroll
      for (int k = 0; k < 8; ++k) {
        float hv = h2f(g8[k]) * (xbar[cc][k] - sc8[k]) + h2f(b8[k]);
        int row = px0 + k;
        int col = ((((c >> 3) + (row >> 2)) & 7) << 3) | (c & 7);
        hb[row * 72 + col] = f2h(hv);
      }
    }
  }
  __syncthreads();

  // phase C: a = Wv*hbar + bv (MFMA f16); wave owns 16 px
  int wv = tid >> 6, lane = tid & 63;
  int ln15 = lane & 15, quad = lane >> 4;
  int px = wv * 16 + ln15;
  f16x8 ah[2];
#pragma unroll
  for (int kt = 0; kt < 2; ++kt) {
    int slot = ((kt * 4 + quad) + (px >> 2)) & 7;
    ah[kt] = *(const f16x8*)(hb + px * 72 + (slot << 3));
  }
  const f16x8* wvg = (const f16x8*)wvp_g;
  f32x4 accV[4];
#pragma unroll
  for (int nt = 0; nt < 4; ++nt) accV[nt] = (f32x4){0.f, 0.f, 0.f, 0.f};
#pragma unroll
  for (int nt = 0; nt < 4; ++nt) {
    f16x8 b0 = wvg[(nt * 2 + 0) * 64 + lane];
    f16x8 b1w = wvg[(nt * 2 + 1) * 64 + lane];
    accV[nt] = __builtin_amdgcn_mfma_f32_16x16x32_f16(ah[0], b0, accV[nt],
                                                      0, 0, 0);
    accV[nt] = __builtin_amdgcn_mfma_f32_16x16x32_f16(ah[1], b1w, accV[nt],
                                                      0, 0, 0);
  }
  int pxb = p0 + wv * 16 + quad * 4;
  float av[4][4];
#pragma unroll
  for (int nt = 0; nt < 4; ++nt) {
    int c = nt * 16 + ln15;
    float bvc = bv[c];
    ushort4 o;
    av[nt][0] = accV[nt][0] + bvc; o.x = f2h(av[nt][0]);
    av[nt][1] = accV[nt][1] + bvc; o.y = f2h(av[nt][1]);
    av[nt][2] = accV[nt][2] + bvc; o.z = f2h(av[nt][2]);
    av[nt][3] = accV[nt][3] + bvc; o.w = f2h(av[nt][3]);
    *(ushort4*)(abf + ((size_t)c << 14) + pxb) = o;
  }

  // phase D: per-frame stats of (xh + a); xh L2-hot from phase B
  float sf[16], qf[16];
#pragma unroll
  for (int f = 0; f < 16; ++f) {
    float s = 0.f, q = 0.f;
#pragma unroll
    for (int nt = 0; nt < 4; ++nt) {
      int c = nt * 16 + ln15;
      ushort4 xv = *(const ushort4*)(xh + (((size_t)f * 64 + c) << 14) + pxb);
      float v0 = h2f(xv.x) + av[nt][0], v1 = h2f(xv.y) + av[nt][1];
      float v2 = h2f(xv.z) + av[nt][2], v3 = h2f(xv.w) + av[nt][3];
      s += v0 + v1 + v2 + v3;
      q = fmaf(v0, v0, q); q = fmaf(v1, v1, q);
      q = fmaf(v2, v2, q); q = fmaf(v3, v3, q);
    }
    sf[f] = s; qf[f] = q;
  }
#pragma unroll
  for (int off = 32; off > 0; off >>= 1) {
#pragma unroll
    for (int f = 0; f < 16; ++f) {
      sf[f] += __shfl_down(sf[f], off);
      qf[f] += __shfl_down(qf[f], off);
    }
  }
  if (lane == 0) {
#pragma unroll
    for (int f = 0; f < 16; ++f) {
      lsq[wv][2 * f] = sf[f];
      lsq[wv][2 * f + 1] = qf[f];
    }
  }
  __syncthreads();
  if (tid < 32) {
    int bkt = blockIdx.x & (NB - 1);
    atomicAdd(&accB[bkt * 32 + tid],
              lsq[0][tid] + lsq[1][tid] + lsq[2][tid] + lsq[3][tid]);
  }
}

// ---- fused attn-add + LN2 + FFN + residual + stats, 128 px/block ----
// LDS: xa[64][132] f32 (33792) | hb[128][72] rot (18432) / f1 overlays /
// vb[64][128] fp16 staging (16384, overlays f1 after GEMM2 reads).
// Reads fp16 xh; d<3: LDS-staged contiguous fp16 writeback to xh;
// d==3: direct f32 stores to xout.
__global__ __launch_bounds__(256) void ffn_kernel(
    u16* __restrict__ xh, float* __restrict__ xout,
    const u16* __restrict__ ap, const float* __restrict__ g,
    const float* __restrict__ bln, const u16* __restrict__ w1p_g,
    const float* __restrict__ b1, const u16* __restrict__ w2p_g,
    const float* __restrict__ b2, const float* __restrict__ accB,
    float* __restrict__ accA, int last) {
  __shared__ __align__(16) char lds[66560];
  float* xaf = (float*)lds;       // [64 c][132 px-padded] f32
  u16* hb = (u16*)(lds + 33792);  // [128][72] chunk-rotated
  u16* f1 = (u16*)(lds + 33792);  // [128][128] swz, overlays hb
  u16* vb = (u16*)(lds + 33792);  // [64 c][128 px] rotated, overlays f1

  int tid = threadIdx.x;
  int P0 = blockIdx.x << 7;
  int l = P0 >> 14;
  int p0 = P0 & 16383;
  int lane = tid & 63;
  float mu, r;
  ln_from_acc_wave(accB, l, lane, mu, r);

  // stage: xa = xh + a -> LDS f32; h = LN(xa) -> hb (chunk-rotated)
#pragma unroll
  for (int it = 0; it < 2; ++it) {
    int pq = tid & 31, cg = (tid >> 5) + it * 8;
    int px = pq * 4, c0 = cg * 4;
    float vv[4][4];
#pragma unroll
    for (int i = 0; i < 4; ++i) {
      int c = c0 + i;
      size_t gi = (((size_t)l * 64 + c) << 14) + p0 + px;
      int li = (c << 14) + p0 + px;
      ushort4 xv = *(const ushort4*)(xh + gi);
      ushort4 av4 = *(const ushort4*)(ap + li);
      float4 gv = *(const float4*)(g + li);
      float4 bb = *(const float4*)(bln + li);
      float4 s4;
      s4.x = h2f(xv.x) + h2f(av4.x);
      s4.y = h2f(xv.y) + h2f(av4.y);
      s4.z = h2f(xv.z) + h2f(av4.z);
      s4.w = h2f(xv.w) + h2f(av4.w);
      *(float4*)(xaf + c * 132 + px) = s4;
      vv[i][0] = (s4.x - mu) * r * gv.x + bb.x;
      vv[i][1] = (s4.y - mu) * r * gv.y + bb.y;
      vv[i][2] = (s4.z - mu) * r * gv.z + bb.z;
      vv[i][3] = (s4.w - mu) * r * gv.w + bb.w;
    }
#pragma unroll
    for (int k = 0; k < 4; ++k) {
      int row = px + k;
      int col = ((((c0 >> 3) + (row >> 2)) & 7) << 3) | (c0 & 7);
      ushort4 hv;
      hv.x = f2h(vv[0][k]); hv.y = f2h(vv[1][k]);
      hv.z = f2h(vv[2][k]); hv.w = f2h(vv[3][k]);
      *(ushort4*)(hb + row * 72 + col) = hv;
    }
  }
  __syncthreads();

  int wv = tid >> 6;
  int ln15 = lane & 15, quad = lane >> 4;

  f16x8 bh[2][2];
#pragma unroll
  for (int nt = 0; nt < 2; ++nt) {
    int px = (wv * 2 + nt) * 16 + ln15;
#pragma unroll
    for (int kt = 0; kt < 2; ++kt) {
      int slot = ((kt * 4 + quad) + (px >> 2)) & 7;
      bh[nt][kt] = *(const f16x8*)(hb + px * 72 + (slot << 3));
    }
  }
  __syncthreads();  // all hb reads drained; f1 may now overwrite

  const f16x8* w1g = (const f16x8*)w1p_g;
  const f16x8* w2g = (const f16x8*)w2p_g;

  // GEMM1 per o-tile mt
#pragma unroll
  for (int mt = 0; mt < 8; ++mt) {
    f16x8 a1a = w1g[(mt * 2 + 0) * 64 + lane];
    f16x8 a1b = w1g[(mt * 2 + 1) * 64 + lane];
    f32x4 acc[2];
    acc[0] = (f32x4){0.f, 0.f, 0.f, 0.f};
    acc[1] = (f32x4){0.f, 0.f, 0.f, 0.f};
#pragma unroll
    for (int nt = 0; nt < 2; ++nt) {
      acc[nt] = __builtin_amdgcn_mfma_f32_16x16x32_f16(a1a, bh[nt][0],
                                                       acc[nt], 0, 0, 0);
      acc[nt] = __builtin_amdgcn_mfma_f32_16x16x32_f16(a1b, bh[nt][1],
                                                       acc[nt], 0, 0, 0);
    }
    int o0 = mt * 16 + quad * 4;
    float4 b1v = *(const float4*)(b1 + o0);
#pragma unroll
    for (int nt = 0; nt < 2; ++nt) {
      int px = (wv * 2 + nt) * 16 + ln15;
      int swz = (px & 7) * 8;
      float fv[4];
#pragma unroll
      for (int rj = 0; rj < 4; ++rj) {
        float f = acc[nt][rj] + ((const float*)&b1v)[rj];
        fv[rj] = fmaxf(f, 0.01f * f);
      }
      int col = ((o0 & ~7) ^ swz) + (o0 & 7);
      ushort4 ov;
      ov.x = f2h(fv[0]); ov.y = f2h(fv[1]);
      ov.z = f2h(fv[2]); ov.w = f2h(fv[3]);
      *(ushort4*)(f1 + px * 128 + col) = ov;
    }
  }
  __syncthreads();

  // GEMM2 transposed
  f16x8 a2[2][4];
#pragma unroll
  for (int mt = 0; mt < 2; ++mt) {
    int px = (wv * 2 + mt) * 16 + ln15;
    int swz = (px & 7) * 8;
#pragma unroll
    for (int kt = 0; kt < 4; ++kt)
      a2[mt][kt] =
          *(const f16x8*)(f1 + px * 128 + ((kt * 32 + quad * 8) ^ swz));
  }
  __syncthreads();  // all f1 reads done; vb may overwrite
  f32x4 acc2[2][4];
#pragma unroll
  for (int mt = 0; mt < 2; ++mt)
#pragma unroll
    for (int nt = 0; nt < 4; ++nt) acc2[mt][nt] = (f32x4){0.f, 0.f, 0.f, 0.f};
#pragma unroll
  for (int nt = 0; nt < 4; ++nt) {
    f16x8 bw[4];
#pragma unroll
    for (int kt = 0; kt < 4; ++kt) bw[kt] = w2g[(nt * 4 + kt) * 64 + lane];
#pragma unroll
    for (int mt = 0; mt < 2; ++mt)
#pragma unroll
      for (int kt = 0; kt < 4; ++kt)
        acc2[mt][nt] = __builtin_amdgcn_mfma_f32_16x16x32_f16(
            a2[mt][kt], bw[kt], acc2[mt][nt], 0, 0, 0);
  }

  // epilogue: v = xa(LDS) + ffn_out; stats; store
  float s = 0.f, q = 0.f;
#pragma unroll
  for (int mt = 0; mt < 2; ++mt) {
    int pxl = (wv * 2 + mt) * 16 + quad * 4;
#pragma unroll
    for (int nt = 0; nt < 4; ++nt) {
      int c = nt * 16 + ln15;
      float b2c = b2[c];
      const float* xac = xaf + c * 132 + pxl;
      float4 v;
      v.x = xac[0] + acc2[mt][nt][0] + b2c;
      v.y = xac[1] + acc2[mt][nt][1] + b2c;
      v.z = xac[2] + acc2[mt][nt][2] + b2c;
      v.w = xac[3] + acc2[mt][nt][3] + b2c;
      if (last) {
        size_t gi = (((size_t)l * 64 + c) << 14) + p0 + pxl;
        *(float4*)(xout + gi) = v;
      } else {
        ushort4 o;
        o.x = f2h(v.x); o.y = f2h(v.y); o.z = f2h(v.z); o.w = f2h(v.w);
        int addr = c * 128 + ((((pxl >> 3) + c) & 15) << 3) + (pxl & 7);
        *(ushort4*)(vb + addr) = o;
      }
      s += v.x + v.y + v.z + v.w;
      q = fmaf(v.x, v.x, q); q = fmaf(v.y, v.y, q);
      q = fmaf(v.z, v.z, q); q = fmaf(v.w, v.w, q);
    }
  }
  if (!last) {
    __syncthreads();
    // contiguous writeback: thread -> 64B (32 px) of one c-plane
    int c = tid >> 2, pb = (tid & 3) << 5;
    size_t gb = (((size_t)l * 64 + c) << 14) + p0 + pb;
#pragma unroll
    for (int k = 0; k < 4; ++k) {
      int ci = (pb >> 3) + k;
      u16x8 v = *(const u16x8*)(vb + c * 128 + (((ci + c) & 15) << 3));
      *(u16x8*)(xh + gb + k * 8) = v;
    }
  }
#pragma unroll
  for (int off = 32; off > 0; off >>= 1) {
    s += __shfl_down(s, off); q += __shfl_down(q, off);
  }
  if (lane == 0) {
    int bkt = blockIdx.x & (NB - 1);
    atomicAdd(&accA[bkt * 32 + l * 2], s);
    atomicAdd(&accA[bkt * 32 + l * 2 + 1], q);
  }
}

extern "C" void kernel_launch(void* const* d_in, const int* in_sizes, int n_in,
                              void* d_out, int out_size, void* d_ws,
                              size_t ws_size, hipStream_t stream) {
  const float* x_in = (const float*)d_in[0];
  const float* ln1_g = (const float*)d_in[1];
  const float* ln1_b = (const float*)d_in[2];
  const float* Wk = (const float*)d_in[5];
  const float* Wv = (const float*)d_in[7];
  const float* bv = (const float*)d_in[8];
  const float* Wa = (const float*)d_in[9];
  const float* ln2_g = (const float*)d_in[11];
  const float* ln2_b = (const float*)d_in[12];
  const float* W1 = (const float*)d_in[13];
  const float* b1 = (const float*)d_in[14];
  const float* W2 = (const float*)d_in[15];
  const float* b2 = (const float*)d_in[16];

  float* xout = (float*)d_out;
  char* wsb = (char*)d_ws;
  u16* xh = (u16*)wsb;                      // 33,554,432 B (fp16 x)
  u16* T = (u16*)(wsb + 33554432);          // 13,107,200 B
  u16* abf = (u16*)(wsb + 46661632);        // 2,097,152 B
  u16* g1b = (u16*)(wsb + 48758784);        // 8,388,608 B
  u16* b1b = (u16*)(wsb + 57147392);        // 8,388,608 B
  u16* w1pk = (u16*)(wsb + 65536000);       // 65,536 B
  u16* w2pk = (u16*)(wsb + 65601536);       // 65,536 B
  u16* wvpk = (u16*)(wsb + 65667072);       // 32,768 B
  u16* wepk = (u16*)(wsb + 65699840);       // 16,384 B
  float* mulr = (float*)(wsb + 65716224);   // 128 B
  float* accA = (float*)(wsb + 65716352);   // 8,192 B
  float* accB = (float*)(wsb + 65724544);   // 8,192 B

  hipMemsetAsync(accA, 0, 16384, stream);  // accA + accB
  prep_kernel<<<dim3(4, 16), 256, 0, stream>>>(Wa, Wk, Wv, W1, W2, w1pk, w2pk,
                                               wvpk, wepk);
  lngb_kernel<<<dim3(4096, 2), 256, 0, stream>>>(ln1_g, ln1_b, g1b, b1b);
  stats_kernel<<<4096, 256, 0, stream>>>(x_in, xh, accA);

  for (int d = 0; d < 4; ++d) {
    tb_kernel<<<dim3(128, 16), 256, 0, stream>>>(
        xh, g1b + (size_t)d * CHW, b1b + (size_t)d * CHW, wepk + d * 2048,
        accA, accB, mulr, T);
    attnc_kernel<<<256, 256, 0, stream>>>(
        xh, T, g1b + (size_t)d * CHW, b1b + (size_t)d * CHW, wvpk + d * 4096,
        bv + d * 64, mulr, abf, accB, accA);
    ffn_kernel<<<2048, 256, 0, stream>>>(
        xh, xout, abf, ln2_g + (size_t)d * CHW, ln2_b + (size_t)d * CHW,
        w1pk + d * 8192, b1 + d * 128, w2pk + d * 8192, b2 + d * 64, accB,
        accA, d == 3 ? 1 : 0);
  }
}

// Round 16
// 506.547 us; speedup vs baseline: 1.0107x; 1.0107x over previous
//
#include <hip/hip_runtime.h>

// Encoder: D=4, L=16, C=64, H=W=128.
// Math: softmax_j(A_i+B_j+ba)==softmax_j(B_j); attn identical for all i;
// B = conv5(h,Weff) as GEMM into 25 tap planes T + shift-add;
// a = Wv*(g1*(sum_j P_j r_j x_j - sum_j P_j r_j mu_j)+b1)+bv.
// R17: full fp16 datapath, 511us. R18: LDS-staged writebacks in tb+ffn ->
// flat total BUT the split showed tb's staged T writeback SAVED ~44us
// (contiguous T for attnc's gather) while ffn's staging COST ~44us
// (writes are posted; ffn wasn't BW-bound, the extra syncs serialized).
// R19 (this): keep tb's staged T writeback; revert ffn to direct stores
// (R14 epilogue — write inflation is harmless when not BW-saturated).

#define HW 16384
#define CHW 1048576
#define NB 64  // stat buckets; each bucket = 32 floats = one 128B line

typedef unsigned short u16;
typedef __attribute__((ext_vector_type(8))) _Float16 f16x8;
typedef __attribute__((ext_vector_type(8))) unsigned short u16x8;
typedef __attribute__((ext_vector_type(4))) float f32x4;

static __device__ __forceinline__ u16 f2h(float f) {
  union { _Float16 h; u16 u; } v;
  v.h = (_Float16)f;
  return v.u;
}
static __device__ __forceinline__ float h2f(u16 u) {
  union { u16 u; _Float16 h; } v;
  v.u = u;
  return (float)v.h;
}
// LN stats from bucketed accumulators, wave-parallel.
static __device__ __forceinline__ void ln_from_acc_wave(
    const float* acc, int l, int lane, float& mu, float& r) {
  const float invN = 1.f / 1048576.f;
  float2 v = *(const float2*)(acc + lane * 32 + 2 * l);
  float s = v.x, q = v.y;
#pragma unroll
  for (int off = 32; off > 0; off >>= 1) {
    s += __shfl_xor(s, off);
    q += __shfl_xor(q, off);
  }
  mu = s * invN;
  r = rsqrtf(q * invN - mu * mu + 1e-5f);
}

// ---- precompute fp16 MFMA fragment packs:
// pack[((t0*KT+kt)*64+lane)*8+j] = W[m=t0*16+(lane&15)][k=kt*32+(lane>>4)*8+j]
__global__ __launch_bounds__(256) void prep_kernel(
    const float* __restrict__ Wa, const float* __restrict__ Wk,
    const float* __restrict__ Wv, const float* __restrict__ W1,
    const float* __restrict__ W2, u16* __restrict__ w1pk,
    u16* __restrict__ w2pk, u16* __restrict__ wvpk, u16* __restrict__ wepk) {
  int d = blockIdx.x;
  int t = blockIdx.y * 256 + threadIdx.x;  // 0..4095
  const int STR = 256 * 16;
  const float* WaK = Wa + ((size_t)d * 128 + 64) * 25;
  const float* Wkd = Wk + d * 4096;
  for (int idx = t; idx < 2048; idx += STR) {  // Weff: m=tap(32), k=ci(64)
    int frag = idx >> 9, lane = (idx >> 3) & 63, j = idx & 7;
    int mt = frag >> 1, kt = frag & 1;
    int tap = mt * 16 + (lane & 15);
    int ci = kt * 32 + (lane >> 4) * 8 + j;
    float s = 0.f;
    if (tap < 25)
      for (int co = 0; co < 64; ++co)
        s = fmaf(WaK[co * 25 + tap], Wkd[co * 64 + ci], s);
    wepk[d * 2048 + idx] = f2h(s);
  }
  const float* Wvd = Wv + d * 4096;
  for (int idx = t; idx < 4096; idx += STR) {  // Wv: m=co(64), k=ci(64)
    int frag = idx >> 9, lane = (idx >> 3) & 63, j = idx & 7;
    int mt = frag >> 1, kt = frag & 1;
    int co = mt * 16 + (lane & 15);
    int ci = kt * 32 + (lane >> 4) * 8 + j;
    wvpk[d * 4096 + idx] = f2h(Wvd[co * 64 + ci]);
  }
  const float* W1d = W1 + d * 8192;
  for (int idx = t; idx < 8192; idx += STR) {  // W1: m=o(128), k=ci(64)
    int frag = idx >> 9, lane = (idx >> 3) & 63, j = idx & 7;
    int mt = frag >> 1, kt = frag & 1;
    int o = mt * 16 + (lane & 15);
    int ci = kt * 32 + (lane >> 4) * 8 + j;
    w1pk[d * 8192 + idx] = f2h(W1d[o * 64 + ci]);
  }
  const float* W2d = W2 + d * 8192;
  for (int idx = t; idx < 8192; idx += STR) {  // W2: m=c(64), k=o(128)
    int frag = idx >> 9, lane = (idx >> 3) & 63, j = idx & 7;
    int mt2 = frag >> 2, kt2 = frag & 3;
    int c = mt2 * 16 + (lane & 15);
    int o = kt2 * 32 + (lane >> 4) * 8 + j;
    w2pk[d * 8192 + idx] = f2h(W2d[c * 128 + o]);
  }
}

// ---- convert g1, b1 (all depths) to fp16 ----
__global__ __launch_bounds__(256) void lngb_kernel(
    const float* __restrict__ g1, const float* __restrict__ b1,
    u16* __restrict__ o1, u16* __restrict__ o2) {
  int idx = blockIdx.x * 256 + threadIdx.x;  // x4 elems
  const float* src = blockIdx.y == 0 ? g1 : b1;
  u16* dst = blockIdx.y == 0 ? o1 : o2;
  float4 v = *(const float4*)(src + (size_t)idx * 4);
  ushort4 o;
  o.x = f2h(v.x); o.y = f2h(v.y); o.z = f2h(v.z); o.w = f2h(v.w);
  *(ushort4*)(dst + (size_t)idx * 4) = o;
}

// ---- per-frame stats of x_in (bucketed) + xh fp16 write ----
__global__ __launch_bounds__(256) void stats_kernel(
    const float* __restrict__ xin, u16* __restrict__ xh,
    float* __restrict__ acc) {
  int tid = threadIdx.x;
  size_t base = (size_t)blockIdx.x * 4096;
  const float4* in4 = (const float4*)(xin + base);
  float s = 0.f, q = 0.f;
#pragma unroll
  for (int k = 0; k < 4; ++k) {
    float4 v = in4[k * 256 + tid];
    ushort4 o;
    o.x = f2h(v.x); o.y = f2h(v.y); o.z = f2h(v.z); o.w = f2h(v.w);
    *(ushort4*)(xh + base + (k * 256 + tid) * 4) = o;
    s += v.x + v.y + v.z + v.w;
    q = fmaf(v.x, v.x, q); q = fmaf(v.y, v.y, q);
    q = fmaf(v.z, v.z, q); q = fmaf(v.w, v.w, q);
  }
#pragma unroll
  for (int off = 32; off > 0; off >>= 1) {
    s += __shfl_down(s, off); q += __shfl_down(q, off);
  }
  __shared__ float ls[4], lq[4];
  int wave = tid >> 6;
  if ((tid & 63) == 0) { ls[wave] = s; lq[wave] = q; }
  __syncthreads();
  if (tid == 0) {
    int frame = blockIdx.x >> 8;
    int bkt = blockIdx.x & (NB - 1);
    atomicAdd(&acc[bkt * 32 + frame * 2], ls[0] + ls[1] + ls[2] + ls[3]);
    atomicAdd(&acc[bkt * 32 + frame * 2 + 1], lq[0] + lq[1] + lq[2] + lq[3]);
  }
}

// ---- LN1 + T GEMM (all fp16), 128 px/block; LDS-staged T writeback ----
// LDS: hb[128][72] (18432) | Tb[25][128] rotated (6400). 24832 B.
__global__ __launch_bounds__(256) void tb_kernel(
    const u16* __restrict__ xh, const u16* __restrict__ g,
    const u16* __restrict__ bln, const u16* __restrict__ wep_g,
    const float* __restrict__ accA, float* __restrict__ accBz,
    float* __restrict__ mulr, u16* __restrict__ T) {
  __shared__ __align__(16) char lds[24832];
  u16* hb = (u16*)lds;
  u16* Tb = (u16*)(lds + 18432);
  int tid = threadIdx.x;
  int l = blockIdx.y;
  int p0 = blockIdx.x << 7;
  if (blockIdx.x == 0 && blockIdx.y == 0)
    for (int i = tid; i < NB * 32; i += 256) accBz[i] = 0.f;
  int lane = tid & 63;
  float mu, r;
  ln_from_acc_wave(accA, l, lane, mu, r);
  if (blockIdx.x == 0 && tid == 0) {
    mulr[2 * l] = mu;
    mulr[2 * l + 1] = r;
  }

  // stage h[px][ci]: thread = (pq: 8px, cg: 4c); u16x8 loads everywhere
  {
    int pq = tid & 15, cg = tid >> 4;
    int px0 = pq * 8, c0 = cg * 4;
    float vv[4][8];
#pragma unroll
    for (int i = 0; i < 4; ++i) {
      int c = c0 + i;
      size_t gi = (((size_t)l * 64 + c) << 14) + p0 + px0;
      int li = (c << 14) + p0 + px0;
      u16x8 xv = *(const u16x8*)(xh + gi);
      u16x8 gv = *(const u16x8*)(g + li);
      u16x8 b8 = *(const u16x8*)(bln + li);
#pragma unroll
      for (int k = 0; k < 8; ++k)
        vv[i][k] = (h2f(xv[k]) - mu) * r * h2f(gv[k]) + h2f(b8[k]);
    }
#pragma unroll
    for (int k = 0; k < 8; ++k) {
      int row = px0 + k;
      int col = ((((c0 >> 3) + (row >> 2)) & 7) << 3) | (c0 & 7);
      ushort4 hv;
      hv.x = f2h(vv[0][k]); hv.y = f2h(vv[1][k]);
      hv.z = f2h(vv[2][k]); hv.w = f2h(vv[3][k]);
      *(ushort4*)(hb + row * 72 + col) = hv;
    }
  }
  __syncthreads();

  int wv = tid >> 6;
  int ln15 = lane & 15, quad = lane >> 4;

  f16x8 ah[2][2];
#pragma unroll
  for (int mt = 0; mt < 2; ++mt) {
    int px = (wv * 2 + mt) * 16 + ln15;
#pragma unroll
    for (int kt = 0; kt < 2; ++kt) {
      int slot = ((kt * 4 + quad) + (px >> 2)) & 7;
      ah[mt][kt] = *(const f16x8*)(hb + px * 72 + (slot << 3));
    }
  }
  const f16x8* weg = (const f16x8*)wep_g;

  f32x4 accT[2][2];
#pragma unroll
  for (int mt = 0; mt < 2; ++mt)
#pragma unroll
    for (int nt = 0; nt < 2; ++nt) accT[mt][nt] = (f32x4){0.f, 0.f, 0.f, 0.f};
#pragma unroll
  for (int nt = 0; nt < 2; ++nt) {
    f16x8 b0 = weg[(nt * 2 + 0) * 64 + lane];
    f16x8 b1w = weg[(nt * 2 + 1) * 64 + lane];
#pragma unroll
    for (int mt = 0; mt < 2; ++mt) {
      accT[mt][nt] = __builtin_amdgcn_mfma_f32_16x16x32_f16(
          ah[mt][0], b0, accT[mt][nt], 0, 0, 0);
      accT[mt][nt] = __builtin_amdgcn_mfma_f32_16x16x32_f16(
          ah[mt][1], b1w, accT[mt][nt], 0, 0, 0);
    }
  }

  // stage T tile into LDS (chunk-rotated), then contiguous writeback
#pragma unroll
  for (int mt = 0; mt < 2; ++mt) {
    int pxl = (wv * 2 + mt) * 16 + quad * 4;  // local px
#pragma unroll
    for (int nt = 0; nt < 2; ++nt) {
      int tap = nt * 16 + ln15;
      if (tap < 25) {
        ushort4 o;
        o.x = f2h(accT[mt][nt][0]); o.y = f2h(accT[mt][nt][1]);
        o.z = f2h(accT[mt][nt][2]); o.w = f2h(accT[mt][nt][3]);
        int addr = tap * 128 + ((((pxl >> 3) + tap) & 15) << 3) + (pxl & 7);
        *(ushort4*)(Tb + addr) = o;
      }
    }
  }
  __syncthreads();
  for (int idx = tid; idx < 400; idx += 256) {
    int tap = idx >> 4, k = idx & 15;
    u16x8 v = *(const u16x8*)(Tb + tap * 128 + (((k + tap) & 15) << 3));
    *(u16x8*)(T + (((size_t)l * 25 + tap) << 14) + p0 + k * 8) = v;
  }
}

// ---- fused B-from-T + softmax + hbar + Wv-GEMM + stats(x+a) ----
// 64px tile/block, grid 256. Phase A1 folds bconv (T L2-hot); phase D
// computes LN2 stats from xh (L2-hot after phase B).
__global__ __launch_bounds__(256) void attnc_kernel(
    const u16* __restrict__ xh, const u16* __restrict__ T,
    const u16* __restrict__ g1, const u16* __restrict__ b1g,
    const u16* __restrict__ wvp_g, const float* __restrict__ bv,
    const float* __restrict__ mulr, u16* __restrict__ abf,
    float* __restrict__ accB, float* __restrict__ accAz) {
  __shared__ float Bsm[16][68];
  __shared__ float Prl[16][64];
  __shared__ float scal[64];
  __shared__ __align__(16) u16 hb[64 * 72];
  __shared__ float lsq[4][32];
  int tid = threadIdx.x;
  int p0 = blockIdx.x << 6;
  if (blockIdx.x == 0)  // zero accA buckets for ffn
    for (int i = tid; i < NB * 32; i += 256) accAz[i] = 0.f;

  // phase A1: B[j][px] = sum_tap T[j][tap][px+off] (fused bconv)
  {
    int j = tid >> 4, xg = tid & 15;
    int y0 = p0 >> 7, x0 = p0 & 127;
    float acc4[4] = {0.f, 0.f, 0.f, 0.f};
    const u16* Tj = T + (((size_t)j * 25) << 14);
#pragma unroll
    for (int dy = 0; dy < 5; ++dy) {
      int yy = y0 + dy - 2;
      if (yy < 0 || yy > 127) continue;
#pragma unroll
      for (int dx = 0; dx < 5; ++dx) {
        const u16* Tt = Tj + ((dy * 5 + dx) << 14) + (yy << 7);
#pragma unroll
        for (int k = 0; k < 4; ++k) {
          int xc = x0 + xg * 4 + k + dx - 2;
          if (xc >= 0 && xc < 128) acc4[k] += h2f(Tt[xc]);
        }
      }
    }
#pragma unroll
    for (int k = 0; k < 4; ++k) Bsm[j][xg * 4 + k] = acc4[k];
  }
  __syncthreads();

  // phase A2: softmax weights (threads 0..63 own one px each)
  if (tid < 64) {
    float bj[16], m = -1e30f;
#pragma unroll
    for (int j = 0; j < 16; ++j) {
      bj[j] = Bsm[j][tid];
      m = fmaxf(m, bj[j]);
    }
    float sum = 0.f;
#pragma unroll
    for (int j = 0; j < 16; ++j) {
      bj[j] = __expf(bj[j] - m);
      sum += bj[j];
    }
    float inv = 1.f / sum;
    float sc = 0.f;
#pragma unroll
    for (int j = 0; j < 16; ++j) {
      float mu_j = mulr[2 * j], r_j = mulr[2 * j + 1];
      float prl = bj[j] * inv * r_j;
      Prl[j][tid] = prl;
      sc = fmaf(prl, mu_j, sc);
    }
    scal[tid] = sc;
  }
  __syncthreads();

  // phase B: xbar = sum_j Prl[j]*xh_j ; hbar = g1*(xbar-scal)+b1 -> hb
  {
    int c2 = tid >> 3, pxg = tid & 7;
    int px0 = pxg * 8;
    float xbar[2][8];
#pragma unroll
    for (int cc = 0; cc < 2; ++cc)
#pragma unroll
      for (int k = 0; k < 8; ++k) xbar[cc][k] = 0.f;
#pragma unroll
    for (int j = 0; j < 16; ++j) {
      float p8[8];
#pragma unroll
      for (int k = 0; k < 8; ++k) p8[k] = Prl[j][px0 + k];
#pragma unroll
      for (int cc = 0; cc < 2; ++cc) {
        int c = cc * 32 + c2;
        u16x8 xv =
            *(const u16x8*)(xh + (((size_t)j * 64 + c) << 14) + p0 + px0);
#pragma unroll
        for (int k = 0; k < 8; ++k)
          xbar[cc][k] = fmaf(p8[k], h2f(xv[k]), xbar[cc][k]);
      }
    }
    float sc8[8];
#pragma unroll
    for (int k = 0; k < 8; ++k) sc8[k] = scal[px0 + k];
#pragma unroll
    for (int cc = 0; cc < 2; ++cc) {
      int c = cc * 32 + c2;
      int li = (c << 14) + p0 + px0;
      u16x8 g8 = *(const u16x8*)(g1 + li);
      u16x8 b8 = *(const u16x8*)(b1g + li);
#pragma unroll
      for (int k = 0; k < 8; ++k) {
        float hv = h2f(g8[k]) * (xbar[cc][k] - sc8[k]) + h2f(b8[k]);
        int row = px0 + k;
        int col = ((((c >> 3) + (row >> 2)) & 7) << 3) | (c & 7);
        hb[row * 72 + col] = f2h(hv);
      }
    }
  }
  __syncthreads();

  // phase C: a = Wv*hbar + bv (MFMA f16); wave owns 16 px
  int wv = tid >> 6, lane = tid & 63;
  int ln15 = lane & 15, quad = lane >> 4;
  int px = wv * 16 + ln15;
  f16x8 ah[2];
#pragma unroll
  for (int kt = 0; kt < 2; ++kt) {
    int slot = ((kt * 4 + quad) + (px >> 2)) & 7;
    ah[kt] = *(const f16x8*)(hb + px * 72 + (slot << 3));
  }
  const f16x8* wvg = (const f16x8*)wvp_g;
  f32x4 accV[4];
#pragma unroll
  for (int nt = 0; nt < 4; ++nt) accV[nt] = (f32x4){0.f, 0.f, 0.f, 0.f};
#pragma unroll
  for (int nt = 0; nt < 4; ++nt) {
    f16x8 b0 = wvg[(nt * 2 + 0) * 64 + lane];
    f16x8 b1w = wvg[(nt * 2 + 1) * 64 + lane];
    accV[nt] = __builtin_amdgcn_mfma_f32_16x16x32_f16(ah[0], b0, accV[nt],
                                                      0, 0, 0);
    accV[nt] = __builtin_amdgcn_mfma_f32_16x16x32_f16(ah[1], b1w, accV[nt],
                                                      0, 0, 0);
  }
  int pxb = p0 + wv * 16 + quad * 4;
  float av[4][4];
#pragma unroll
  for (int nt = 0; nt < 4; ++nt) {
    int c = nt * 16 + ln15;
    float bvc = bv[c];
    ushort4 o;
    av[nt][0] = accV[nt][0] + bvc; o.x = f2h(av[nt][0]);
    av[nt][1] = accV[nt][1] + bvc; o.y = f2h(av[nt][1]);
    av[nt][2] = accV[nt][2] + bvc; o.z = f2h(av[nt][2]);
    av[nt][3] = accV[nt][3] + bvc; o.w = f2h(av[nt][3]);
    *(ushort4*)(abf + ((size_t)c << 14) + pxb) = o;
  }

  // phase D: per-frame stats of (xh + a); xh L2-hot from phase B
  float sf[16], qf[16];
#pragma unroll
  for (int f = 0; f < 16; ++f) {
    float s = 0.f, q = 0.f;
#pragma unroll
    for (int nt = 0; nt < 4; ++nt) {
      int c = nt * 16 + ln15;
      ushort4 xv = *(const ushort4*)(xh + (((size_t)f * 64 + c) << 14) + pxb);
      float v0 = h2f(xv.x) + av[nt][0], v1 = h2f(xv.y) + av[nt][1];
      float v2 = h2f(xv.z) + av[nt][2], v3 = h2f(xv.w) + av[nt][3];
      s += v0 + v1 + v2 + v3;
      q = fmaf(v0, v0, q); q = fmaf(v1, v1, q);
      q = fmaf(v2, v2, q); q = fmaf(v3, v3, q);
    }
    sf[f] = s; qf[f] = q;
  }
#pragma unroll
  for (int off = 32; off > 0; off >>= 1) {
#pragma unroll
    for (int f = 0; f < 16; ++f) {
      sf[f] += __shfl_down(sf[f], off);
      qf[f] += __shfl_down(qf[f], off);
    }
  }
  if (lane == 0) {
#pragma unroll
    for (int f = 0; f < 16; ++f) {
      lsq[wv][2 * f] = sf[f];
      lsq[wv][2 * f + 1] = qf[f];
    }
  }
  __syncthreads();
  if (tid < 32) {
    int bkt = blockIdx.x & (NB - 1);
    atomicAdd(&accB[bkt * 32 + tid],
              lsq[0][tid] + lsq[1][tid] + lsq[2][tid] + lsq[3][tid]);
  }
}

// ---- fused attn-add + LN2 + FFN + residual + stats, 128 px/block ----
// LDS: xa[64][132] f32 (33792) | hb[128][72] rot (18432) / f1 overlays.
// Reads fp16 xh; direct stores (writes are posted; inflation harmless).
__global__ __launch_bounds__(256) void ffn_kernel(
    u16* __restrict__ xh, float* __restrict__ xout,
    const u16* __restrict__ ap, const float* __restrict__ g,
    const float* __restrict__ bln, const u16* __restrict__ w1p_g,
    const float* __restrict__ b1, const u16* __restrict__ w2p_g,
    const float* __restrict__ b2, const float* __restrict__ accB,
    float* __restrict__ accA, int last) {
  __shared__ __align__(16) char lds[66560];
  float* xaf = (float*)lds;       // [64 c][132 px-padded] f32
  u16* hb = (u16*)(lds + 33792);  // [128][72] chunk-rotated
  u16* f1 = (u16*)(lds + 33792);  // [128][128] swz, overlays hb

  int tid = threadIdx.x;
  int P0 = blockIdx.x << 7;
  int l = P0 >> 14;
  int p0 = P0 & 16383;
  int lane = tid & 63;
  float mu, r;
  ln_from_acc_wave(accB, l, lane, mu, r);

  // stage: xa = xh + a -> LDS f32; h = LN(xa) -> hb (chunk-rotated)
#pragma unroll
  for (int it = 0; it < 2; ++it) {
    int pq = tid & 31, cg = (tid >> 5) + it * 8;
    int px = pq * 4, c0 = cg * 4;
    float vv[4][4];
#pragma unroll
    for (int i = 0; i < 4; ++i) {
      int c = c0 + i;
      size_t gi = (((size_t)l * 64 + c) << 14) + p0 + px;
      int li = (c << 14) + p0 + px;
      ushort4 xv = *(const ushort4*)(xh + gi);
      ushort4 av4 = *(const ushort4*)(ap + li);
      float4 gv = *(const float4*)(g + li);
      float4 bb = *(const float4*)(bln + li);
      float4 s4;
      s4.x = h2f(xv.x) + h2f(av4.x);
      s4.y = h2f(xv.y) + h2f(av4.y);
      s4.z = h2f(xv.z) + h2f(av4.z);
      s4.w = h2f(xv.w) + h2f(av4.w);
      *(float4*)(xaf + c * 132 + px) = s4;
      vv[i][0] = (s4.x - mu) * r * gv.x + bb.x;
      vv[i][1] = (s4.y - mu) * r * gv.y + bb.y;
      vv[i][2] = (s4.z - mu) * r * gv.z + bb.z;
      vv[i][3] = (s4.w - mu) * r * gv.w + bb.w;
    }
#pragma unroll
    for (int k = 0; k < 4; ++k) {
      int row = px + k;
      int col = ((((c0 >> 3) + (row >> 2)) & 7) << 3) | (c0 & 7);
      ushort4 hv;
      hv.x = f2h(vv[0][k]); hv.y = f2h(vv[1][k]);
      hv.z = f2h(vv[2][k]); hv.w = f2h(vv[3][k]);
      *(ushort4*)(hb + row * 72 + col) = hv;
    }
  }
  __syncthreads();

  int wv = tid >> 6;
  int ln15 = lane & 15, quad = lane >> 4;

  f16x8 bh[2][2];
#pragma unroll
  for (int nt = 0; nt < 2; ++nt) {
    int px = (wv * 2 + nt) * 16 + ln15;
#pragma unroll
    for (int kt = 0; kt < 2; ++kt) {
      int slot = ((kt * 4 + quad) + (px >> 2)) & 7;
      bh[nt][kt] = *(const f16x8*)(hb + px * 72 + (slot << 3));
    }
  }
  __syncthreads();  // all hb reads drained; f1 may now overwrite

  const f16x8* w1g = (const f16x8*)w1p_g;
  const f16x8* w2g = (const f16x8*)w2p_g;

  // GEMM1 per o-tile mt
#pragma unroll
  for (int mt = 0; mt < 8; ++mt) {
    f16x8 a1a = w1g[(mt * 2 + 0) * 64 + lane];
    f16x8 a1b = w1g[(mt * 2 + 1) * 64 + lane];
    f32x4 acc[2];
    acc[0] = (f32x4){0.f, 0.f, 0.f, 0.f};
    acc[1] = (f32x4){0.f, 0.f, 0.f, 0.f};
#pragma unroll
    for (int nt = 0; nt < 2; ++nt) {
      acc[nt] = __builtin_amdgcn_mfma_f32_16x16x32_f16(a1a, bh[nt][0],
                                                       acc[nt], 0, 0, 0);
      acc[nt] = __builtin_amdgcn_mfma_f32_16x16x32_f16(a1b, bh[nt][1],
                                                       acc[nt], 0, 0, 0);
    }
    int o0 = mt * 16 + quad * 4;
    float4 b1v = *(const float4*)(b1 + o0);
#pragma unroll
    for (int nt = 0; nt < 2; ++nt) {
      int px = (wv * 2 + nt) * 16 + ln15;
      int swz = (px & 7) * 8;
      float fv[4];
#pragma unroll
      for (int rj = 0; rj < 4; ++rj) {
        float f = acc[nt][rj] + ((const float*)&b1v)[rj];
        fv[rj] = fmaxf(f, 0.01f * f);
      }
      int col = ((o0 & ~7) ^ swz) + (o0 & 7);
      ushort4 ov;
      ov.x = f2h(fv[0]); ov.y = f2h(fv[1]);
      ov.z = f2h(fv[2]); ov.w = f2h(fv[3]);
      *(ushort4*)(f1 + px * 128 + col) = ov;
    }
  }
  __syncthreads();

  // GEMM2 transposed
  f16x8 a2[2][4];
#pragma unroll
  for (int mt = 0; mt < 2; ++mt) {
    int px = (wv * 2 + mt) * 16 + ln15;
    int swz = (px & 7) * 8;
#pragma unroll
    for (int kt = 0; kt < 4; ++kt)
      a2[mt][kt] =
          *(const f16x8*)(f1 + px * 128 + ((kt * 32 + quad * 8) ^ swz));
  }
  f32x4 acc2[2][4];
#pragma unroll
  for (int mt = 0; mt < 2; ++mt)
#pragma unroll
    for (int nt = 0; nt < 4; ++nt) acc2[mt][nt] = (f32x4){0.f, 0.f, 0.f, 0.f};
#pragma unroll
  for (int nt = 0; nt < 4; ++nt) {
    f16x8 bw[4];
#pragma unroll
    for (int kt = 0; kt < 4; ++kt) bw[kt] = w2g[(nt * 4 + kt) * 64 + lane];
#pragma unroll
    for (int mt = 0; mt < 2; ++mt)
#pragma unroll
      for (int kt = 0; kt < 4; ++kt)
        acc2[mt][nt] = __builtin_amdgcn_mfma_f32_16x16x32_f16(
            a2[mt][kt], bw[kt], acc2[mt][nt], 0, 0, 0);
  }

  // epilogue: v = xa(LDS) + ffn_out; direct stores; stats
  float s = 0.f, q = 0.f;
#pragma unroll
  for (int mt = 0; mt < 2; ++mt) {
    int pxl = (wv * 2 + mt) * 16 + quad * 4;
#pragma unroll
    for (int nt = 0; nt < 4; ++nt) {
      int c = nt * 16 + ln15;
      float b2c = b2[c];
      const float* xac = xaf + c * 132 + pxl;
      float4 v;
      v.x = xac[0] + acc2[mt][nt][0] + b2c;
      v.y = xac[1] + acc2[mt][nt][1] + b2c;
      v.z = xac[2] + acc2[mt][nt][2] + b2c;
      v.w = xac[3] + acc2[mt][nt][3] + b2c;
      size_t gi = (((size_t)l * 64 + c) << 14) + p0 + pxl;
      if (last) {
        *(float4*)(xout + gi) = v;
      } else {
        ushort4 o;
        o.x = f2h(v.x); o.y = f2h(v.y); o.z = f2h(v.z); o.w = f2h(v.w);
        *(ushort4*)(xh + gi) = o;
      }
      s += v.x + v.y + v.z + v.w;
      q = fmaf(v.x, v.x, q); q = fmaf(v.y, v.y, q);
      q = fmaf(v.z, v.z, q); q = fmaf(v.w, v.w, q);
    }
  }
#pragma unroll
  for (int off = 32; off > 0; off >>= 1) {
    s += __shfl_down(s, off); q += __shfl_down(q, off);
  }
  if (lane == 0) {
    int bkt = blockIdx.x & (NB - 1);
    atomicAdd(&accA[bkt * 32 + l * 2], s);
    atomicAdd(&accA[bkt * 32 + l * 2 + 1], q);
  }
}

extern "C" void kernel_launch(void* const* d_in, const int* in_sizes, int n_in,
                              void* d_out, int out_size, void* d_ws,
                              size_t ws_size, hipStream_t stream) {
  const float* x_in = (const float*)d_in[0];
  const float* ln1_g = (const float*)d_in[1];
  const float* ln1_b = (const float*)d_in[2];
  const float* Wk = (const float*)d_in[5];
  const float* Wv = (const float*)d_in[7];
  const float* bv = (const float*)d_in[8];
  const float* Wa = (const float*)d_in[9];
  const float* ln2_g = (const float*)d_in[11];
  const float* ln2_b = (const float*)d_in[12];
  const float* W1 = (const float*)d_in[13];
  const float* b1 = (const float*)d_in[14];
  const float* W2 = (const float*)d_in[15];
  const float* b2 = (const float*)d_in[16];

  float* xout = (float*)d_out;
  char* wsb = (char*)d_ws;
  u16* xh = (u16*)wsb;                      // 33,554,432 B (fp16 x)
  u16* T = (u16*)(wsb + 33554432);          // 13,107,200 B
  u16* abf = (u16*)(wsb + 46661632);        // 2,097,152 B
  u16* g1b = (u16*)(wsb + 48758784);        // 8,388,608 B
  u16* b1b = (u16*)(wsb + 57147392);        // 8,388,608 B
  u16* w1pk = (u16*)(wsb + 65536000);       // 65,536 B
  u16* w2pk = (u16*)(wsb + 65601536);       // 65,536 B
  u16* wvpk = (u16*)(wsb + 65667072);       // 32,768 B
  u16* wepk = (u16*)(wsb + 65699840);       // 16,384 B
  float* mulr = (float*)(wsb + 65716224);   // 128 B
  float* accA = (float*)(wsb + 65716352);   // 8,192 B
  float* accB = (float*)(wsb + 65724544);   // 8,192 B

  hipMemsetAsync(accA, 0, 16384, stream);  // accA + accB
  prep_kernel<<<dim3(4, 16), 256, 0, stream>>>(Wa, Wk, Wv, W1, W2, w1pk, w2pk,
                                               wvpk, wepk);
  lngb_kernel<<<dim3(4096, 2), 256, 0, stream>>>(ln1_g, ln1_b, g1b, b1b);
  stats_kernel<<<4096, 256, 0, stream>>>(x_in, xh, accA);

  for (int d = 0; d < 4; ++d) {
    tb_kernel<<<dim3(128, 16), 256, 0, stream>>>(
        xh, g1b + (size_t)d * CHW, b1b + (size_t)d * CHW, wepk + d * 2048,
        accA, accB, mulr, T);
    attnc_kernel<<<256, 256, 0, stream>>>(
        xh, T, g1b + (size_t)d * CHW, b1b + (size_t)d * CHW, wvpk + d * 4096,
        bv + d * 64, mulr, abf, accB, accA);
    ffn_kernel<<<2048, 256, 0, stream>>>(
        xh, xout, abf, ln2_g + (size_t)d * CHW, ln2_b + (size_t)d * CHW,
        w1pk + d * 8192, b1 + d * 128, w2pk + d * 8192, b2 + d * 64, accB,
        accA, d == 3 ? 1 : 0);
  }
}